// Round 5
// baseline (300.582 us; speedup 1.0000x reference)
//
#include <hip/hip_runtime.h>

typedef __attribute__((ext_vector_type(8))) short short8;
typedef __attribute__((ext_vector_type(4))) float f32x4;
typedef __attribute__((ext_vector_type(16))) float f32x16;
typedef __attribute__((ext_vector_type(4))) unsigned u32x4;

__device__ __forceinline__ unsigned short f2bf(float f) {
  unsigned u = __builtin_bit_cast(unsigned, f);
  u += 0x7fffu + ((u >> 16) & 1u);
  return (unsigned short)(u >> 16);
}

__device__ __forceinline__ unsigned cvt_pk_bf16(float a, float b) {
  unsigned r;
  asm("v_cvt_pk_bf16_f32 %0, %1, %2" : "=v"(r) : "v"(a), "v"(b));
  return r;
}

// ---------------- convert f32 -> bf16 (straight copy) ----------------
__global__ __launch_bounds__(256) void cvt_copy(const float* __restrict__ in,
                                                unsigned short* __restrict__ out,
                                                int n4) {
  int i = blockIdx.x * 256 + threadIdx.x;
  if (i >= n4) return;
  float4 v = ((const float4*)in)[i];
  ushort4 o;
  o.x = f2bf(v.x); o.y = f2bf(v.y); o.z = f2bf(v.z); o.w = f2bf(v.w);
  ((ushort4*)out)[i] = o;
}

// ---------------- transpose + convert: in f32 [R][C] -> out bf16 [C][R] ----------------
__global__ __launch_bounds__(256) void transpose_cvt(const float* __restrict__ in,
                                                     unsigned short* __restrict__ out,
                                                     int R, int C) {
  __shared__ float tile[32][33];
  int c0 = blockIdx.x * 32, r0 = blockIdx.y * 32;
  int tx = threadIdx.x, ty = threadIdx.y;
  for (int i = ty; i < 32; i += 8)
    tile[i][tx] = in[(size_t)(r0 + i) * C + c0 + tx];
  __syncthreads();
  for (int i = ty; i < 32; i += 8)
    out[(size_t)(c0 + i) * R + r0 + tx] = f2bf(tile[tx][i]);
}

// ---------------- bf16 GEMM: C[M][N] = A[M][K] * Bt[N][K]^T ----------------
template <int MODE>
__global__ __launch_bounds__(256) void gemm_bt(
    const unsigned short* __restrict__ A, const unsigned short* __restrict__ Bt,
    unsigned short* __restrict__ out0, unsigned short* __restrict__ out1,
    float* __restrict__ outf, const float* __restrict__ bias,
    int M, int N, int K) {
  __shared__ __align__(16) unsigned short A_lds[128][72];
  __shared__ __align__(16) unsigned short B_lds[128][72];
  const int tile_m = blockIdx.x * 128;
  const int tile_n = blockIdx.y * 128;
  const int tid = threadIdx.x;
  const int wid = tid >> 6, lane = tid & 63;
  const int wm = (wid >> 1) * 64, wn = (wid & 1) * 64;
  const int lr = lane & 15, lg = lane >> 4;
  f32x4 acc[4][4] = {};

  for (int k0 = 0; k0 < K; k0 += 64) {
    __syncthreads();
#pragma unroll
    for (int p = 0; p < 4; ++p) {
      int flat = p * 256 + tid;
      int row = flat >> 3, cg = (flat & 7) << 3;
      *(short8*)&A_lds[row][cg] = *(const short8*)&A[(size_t)(tile_m + row) * K + k0 + cg];
      *(short8*)&B_lds[row][cg] = *(const short8*)&Bt[(size_t)(tile_n + row) * K + k0 + cg];
    }
    __syncthreads();
    short8 a[4][2], b[4][2];
#pragma unroll
    for (int i = 0; i < 4; ++i)
#pragma unroll
      for (int t = 0; t < 2; ++t) {
        a[i][t] = *(const short8*)&A_lds[wm + i * 16 + lr][t * 32 + lg * 8];
        b[i][t] = *(const short8*)&B_lds[wn + i * 16 + lr][t * 32 + lg * 8];
      }
#pragma unroll
    for (int i = 0; i < 4; ++i)
#pragma unroll
      for (int j = 0; j < 4; ++j)
#pragma unroll
        for (int t = 0; t < 2; ++t)
          acc[i][j] = __builtin_amdgcn_mfma_f32_16x16x32_bf16(a[i][t], b[j][t], acc[i][j], 0, 0, 0);
  }

#pragma unroll
  for (int i = 0; i < 4; ++i)
#pragma unroll
    for (int j = 0; j < 4; ++j)
#pragma unroll
      for (int r = 0; r < 4; ++r) {
        int m = tile_m + wm + i * 16 + lg * 4 + r;
        int n = tile_n + wn + j * 16 + lr;
        float v = acc[i][j][r];
        if (MODE == 0) {
          int b = m >> 11, q = m & 2047;
          int h = n >> 6, d = n & 63;
          out0[((size_t)((b * 12 + h) * 2048 + q) << 6) + d] = f2bf(v);
        } else if (MODE == 1) {
          int b = m >> 11, kv = m & 2047;
          if (n < 768) {
            int h = n >> 6, d = n & 63;
            out0[((size_t)((b * 12 + h) * 2048 + kv) << 6) + d] = f2bf(v);
          } else {
            int h = (n - 768) >> 6, d = n & 63;
            out1[((size_t)((b * 12 + h) * 64 + d) << 11) + kv] = f2bf(v);
          }
        } else {
          outf[(size_t)m * N + n] = v + bias[n];
        }
      }
}

// ---------------- flash attention: in-block KV-split x4, reg-resident K/V ----------------
// Q: [B,H,Nq,D] bf16; Kb: [B,H,Nkv,D] bf16; Vt: [B,H,D,Nkv] bf16
// X out: [B,Nq,H*D] bf16.  softmax(QK^T * s) V * s, s = 0.125
// 256 thr = 4 independent waves; wave s handles KV slice [512s, 512s+512) of the
// SAME (bh, q-block) with the no-barrier reg-resident loop. One barrier at the
// end; partials (m, l, O) merged through LDS; wave w writes d-range [16w,16w+16).
__global__ __launch_bounds__(256, 4) void attn_fwd(
    const unsigned short* __restrict__ Q, const unsigned short* __restrict__ Kb,
    const unsigned short* __restrict__ Vt, unsigned short* __restrict__ X) {
  __shared__ __align__(16) float O_lds[4][32][64];
  __shared__ float m_lds[4][32];
  __shared__ float l_lds[4][64];
  const int bid = blockIdx.x;
  const int bh = bid % 24;           // bid%8 == bh%8 -> 3 heads per XCD L2
  const int q0 = (bid / 24) * 32;
  const int tid = threadIdx.x;
  const int wid = tid >> 6;          // KV slice index
  const int lane = tid & 63;
  const int l31 = lane & 31, hi = lane >> 5;
  const int kvS = wid * 512;
  const float Cc = 0.18033688011112042f;   // 0.125 * log2(e)
  const float THRS = 44.3614195558365f;    // 8 / Cc (defer-max threshold)

  const unsigned short* Kbase = Kb + (size_t)bh * (2048 * 64);
  const unsigned short* Vbase = Vt + (size_t)bh * (64 * 2048);

  // Q frags: B-operand; lane holds Q[q=l31][d = t*16 + hi*8 + e]
  short8 qf[4];
  {
    const unsigned short* Qp = Q + ((size_t)bh * 2048 + q0 + l31) * 64 + hi * 8;
#pragma unroll
    for (int t = 0; t < 4; ++t) qf[t] = *(const short8*)&Qp[t * 16];
  }

  f32x16 accO0 = {}, accO1 = {};      // O^T[d = dt*32 + crow(r,hi)][q = l31]
  float m_run = -1e30f, l_run = 0.f;  // l_run: per-half partial sum

  short8 kA[8], kB[8], vf[8];
  // prologue: K rows kvS..+63 -> kA
#pragma unroll
  for (int t = 0; t < 4; ++t) {
    kA[t]     = *(const short8*)&Kbase[(size_t)(kvS + l31) * 64 + t * 16 + hi * 8];
    kA[4 + t] = *(const short8*)&Kbase[(size_t)(kvS + 32 + l31) * 64 + t * 16 + hi * 8];
  }

#define ATTN_BODY(KC, KN, IT)                                                          \
  {                                                                                    \
    const int kv0 = kvS + (IT) * 64;                                                   \
    const int kvn = kvS + (((IT) < 7) ? ((IT) + 1) * 64 : 0);                          \
    _Pragma("unroll")                                                                  \
    for (int t = 0; t < 4; ++t) {                                                      \
      KN[t]     = *(const short8*)&Kbase[(size_t)(kvn + l31) * 64 + t * 16 + hi * 8];  \
      KN[4 + t] = *(const short8*)&Kbase[(size_t)(kvn + 32 + l31) * 64 + t * 16 + hi * 8]; \
    }                                                                                  \
    _Pragma("unroll")                                                                  \
    for (int s = 0; s < 4; ++s) {                                                      \
      vf[s]     = *(const short8*)&Vbase[(size_t)l31 * 2048 + kv0 + s * 16 + hi * 8];  \
      vf[4 + s] = *(const short8*)&Vbase[(size_t)(32 + l31) * 2048 + kv0 + s * 16 + hi * 8]; \
    }                                                                                  \
    f32x16 S0 = {}, S1 = {};                                                           \
    _Pragma("unroll")                                                                  \
    for (int t = 0; t < 4; ++t) {                                                      \
      S0 = __builtin_amdgcn_mfma_f32_32x32x16_bf16(KC[t], qf[t], S0, 0, 0, 0);         \
      S1 = __builtin_amdgcn_mfma_f32_32x32x16_bf16(KC[4 + t], qf[t], S1, 0, 0, 0);     \
    }                                                                                  \
    float rmax = fmaxf(S0[0], S1[0]);                                                  \
    _Pragma("unroll")                                                                  \
    for (int r = 1; r < 16; ++r) rmax = fmaxf(rmax, fmaxf(S0[r], S1[r]));              \
    rmax = fmaxf(rmax, __shfl_xor(rmax, 32));                                          \
    if (!__all(rmax <= m_run + THRS)) {                                                \
      float mnew = fmaxf(m_run, rmax);                                                 \
      float alpha = exp2f((m_run - mnew) * Cc);                                        \
      m_run = mnew;                                                                    \
      l_run *= alpha;                                                                  \
      _Pragma("unroll")                                                                \
      for (int r = 0; r < 16; ++r) { accO0[r] *= alpha; accO1[r] *= alpha; }           \
    }                                                                                  \
    float sum = 0.f;                                                                   \
    _Pragma("unroll")                                                                  \
    for (int r = 0; r < 16; ++r) {                                                     \
      S0[r] = exp2f((S0[r] - m_run) * Cc);                                             \
      S1[r] = exp2f((S1[r] - m_run) * Cc);                                             \
      sum += S0[r] + S1[r];                                                            \
    }                                                                                  \
    l_run += sum;                                                                      \
    unsigned w0[8], w1[8];                                                             \
    _Pragma("unroll")                                                                  \
    for (int j = 0; j < 4; ++j) {                                                      \
      w0[j]     = cvt_pk_bf16(S0[4 * j],     S0[4 * j + 1]);                           \
      w1[j]     = cvt_pk_bf16(S0[4 * j + 2], S0[4 * j + 3]);                           \
      w0[4 + j] = cvt_pk_bf16(S1[4 * j],     S1[4 * j + 1]);                           \
      w1[4 + j] = cvt_pk_bf16(S1[4 * j + 2], S1[4 * j + 3]);                           \
    }                                                                                  \
    _Pragma("unroll")                                                                  \
    for (int s = 0; s < 4; ++s) {                                                      \
      unsigned A0 = w0[2 * s], B0 = w0[2 * s + 1];                                     \
      unsigned A1 = w1[2 * s], B1 = w1[2 * s + 1];                                     \
      unsigned A0s = (unsigned)__shfl_xor((int)A0, 32);                                \
      unsigned B0s = (unsigned)__shfl_xor((int)B0, 32);                                \
      unsigned A1s = (unsigned)__shfl_xor((int)A1, 32);                                \
      unsigned B1s = (unsigned)__shfl_xor((int)B1, 32);                                \
      unsigned X0 = hi ? B0s : A0;                                                     \
      unsigned X1 = hi ? B1s : A1;                                                     \
      unsigned X2 = hi ? B0 : A0s;                                                     \
      unsigned X3 = hi ? B1 : A1s;                                                     \
      u32x4 pw = {X0, X1, X2, X3};                                                     \
      short8 pfrag = __builtin_bit_cast(short8, pw);                                   \
      accO0 = __builtin_amdgcn_mfma_f32_32x32x16_bf16(vf[s], pfrag, accO0, 0, 0, 0);   \
      accO1 = __builtin_amdgcn_mfma_f32_32x32x16_bf16(vf[4 + s], pfrag, accO1, 0, 0, 0); \
    }                                                                                  \
  }

  for (int i = 0; i < 4; ++i) {
    ATTN_BODY(kA, kB, 2 * i);
    ATTN_BODY(kB, kA, 2 * i + 1);
  }
#undef ATTN_BODY

  // ---- write partials to LDS ----
#pragma unroll
  for (int dt = 0; dt < 2; ++dt) {
    const f32x16& acc = dt ? accO1 : accO0;
#pragma unroll
    for (int r = 0; r < 16; ++r)
      O_lds[wid][dt * 16 + r][hi * 32 + l31] = acc[r];
  }
  if (hi == 0) m_lds[wid][l31] = m_run;
  l_lds[wid][hi * 32 + l31] = l_run;
  __syncthreads();

  // ---- combine across slices; wave w covers d in [16w,16w+16), lane: j=hi*8.. ----
  float M = m_lds[0][l31];
#pragma unroll
  for (int s = 1; s < 4; ++s) M = fmaxf(M, m_lds[s][l31]);
  float wsc[4];
  float ltot = 0.f;
#pragma unroll
  for (int s = 0; s < 4; ++s) {
    wsc[s] = exp2f((m_lds[s][l31] - M) * Cc);
    ltot += wsc[s] * (l_lds[s][l31] + l_lds[s][32 + l31]);
  }
  const float inv = 0.125f / ltot;  // faithful quirk: extra scale
  const int b = bh / 12, h = bh % 12;
  short8 os;
#pragma unroll
  for (int j = 0; j < 8; ++j) {
    const int d = wid * 16 + hi * 8 + j;
    const int dt = d >> 5, crow = d & 31;
    const int hs = (crow >> 2) & 1;
    const int r = (crow & 3) | ((crow >> 3) << 2);
    float acc = 0.f;
#pragma unroll
    for (int s = 0; s < 4; ++s) acc += wsc[s] * O_lds[s][dt * 16 + r][hs * 32 + l31];
    os[j] = (short)f2bf(acc * inv);
  }
  unsigned short* Xp = X + ((size_t)b * 2048 + q0 + l31) * 768 + h * 64 + wid * 16 + hi * 8;
  *(short8*)Xp = os;
}

extern "C" void kernel_launch(void* const* d_in, const int* in_sizes, int n_in,
                              void* d_out, int out_size, void* d_ws, size_t ws_size,
                              hipStream_t stream) {
  const float* q_token  = (const float*)d_in[0];
  const float* kv_token = (const float*)d_in[1];
  const float* Wq    = (const float*)d_in[2];
  const float* Wkv   = (const float*)d_in[3];
  const float* Wproj = (const float*)d_in[4];
  const float* bproj = (const float*)d_in[5];
  float* out = (float*)d_out;

  unsigned short* qb   = (unsigned short*)d_ws;   // [4096][768]
  unsigned short* kvb  = qb   + 3145728;          // [4096][768]
  unsigned short* wqT  = kvb  + 3145728;          // [768][768]
  unsigned short* wkvT = wqT  + 589824;           // [1536][768]
  unsigned short* wpT  = wkvT + 1179648;          // [768][768]
  unsigned short* Qb   = wpT  + 589824;           // [B,H,Nq,D]
  unsigned short* Kbf  = Qb   + 3145728;          // [B,H,Nkv,D]
  unsigned short* Vtb  = Kbf  + 3145728;          // [B,H,D,Nkv]
  unsigned short* Xb   = Vtb  + 3145728;          // [B,Nq,C]

  cvt_copy<<<3072, 256, 0, stream>>>(q_token, qb, 786432);
  cvt_copy<<<3072, 256, 0, stream>>>(kv_token, kvb, 786432);
  transpose_cvt<<<dim3(24, 24), dim3(32, 8), 0, stream>>>(Wq, wqT, 768, 768);
  transpose_cvt<<<dim3(48, 24), dim3(32, 8), 0, stream>>>(Wkv, wkvT, 768, 1536);
  transpose_cvt<<<dim3(24, 24), dim3(32, 8), 0, stream>>>(Wproj, wpT, 768, 768);

  gemm_bt<0><<<dim3(32, 6),  256, 0, stream>>>(qb,  wqT,  Qb,  nullptr, nullptr, nullptr, 4096, 768, 768);
  gemm_bt<1><<<dim3(32, 12), 256, 0, stream>>>(kvb, wkvT, Kbf, Vtb,     nullptr, nullptr, 4096, 1536, 768);

  attn_fwd<<<1536, 256, 0, stream>>>(Qb, Kbf, Vtb, Xb);

  gemm_bt<2><<<dim3(32, 6), 256, 0, stream>>>(Xb, wpT, nullptr, nullptr, out, bproj, 4096, 768, 768);
}

// Round 6
// 175.488 us; speedup vs baseline: 1.7128x; 1.7128x over previous
//
#include <hip/hip_runtime.h>

typedef __attribute__((ext_vector_type(8))) short short8;
typedef __attribute__((ext_vector_type(4))) float f32x4;
typedef __attribute__((ext_vector_type(16))) float f32x16;
typedef __attribute__((ext_vector_type(4))) unsigned u32x4;

__device__ __forceinline__ unsigned short f2bf(float f) {
  unsigned u = __builtin_bit_cast(unsigned, f);
  u += 0x7fffu + ((u >> 16) & 1u);
  return (unsigned short)(u >> 16);
}

__device__ __forceinline__ unsigned cvt_pk_bf16(float a, float b) {
  unsigned r;
  asm("v_cvt_pk_bf16_f32 %0, %1, %2" : "=v"(r) : "v"(a), "v"(b));
  return r;
}

// ---------------- convert f32 -> bf16 (straight copy) ----------------
__global__ __launch_bounds__(256) void cvt_copy(const float* __restrict__ in,
                                                unsigned short* __restrict__ out,
                                                int n4) {
  int i = blockIdx.x * 256 + threadIdx.x;
  if (i >= n4) return;
  float4 v = ((const float4*)in)[i];
  ushort4 o;
  o.x = f2bf(v.x); o.y = f2bf(v.y); o.z = f2bf(v.z); o.w = f2bf(v.w);
  ((ushort4*)out)[i] = o;
}

// ---------------- transpose + convert: in f32 [R][C] -> out bf16 [C][R] ----------------
__global__ __launch_bounds__(256) void transpose_cvt(const float* __restrict__ in,
                                                     unsigned short* __restrict__ out,
                                                     int R, int C) {
  __shared__ float tile[32][33];
  int c0 = blockIdx.x * 32, r0 = blockIdx.y * 32;
  int tx = threadIdx.x, ty = threadIdx.y;
  for (int i = ty; i < 32; i += 8)
    tile[i][tx] = in[(size_t)(r0 + i) * C + c0 + tx];
  __syncthreads();
  for (int i = ty; i < 32; i += 8)
    out[(size_t)(c0 + i) * R + r0 + tx] = f2bf(tile[tx][i]);
}

// ---------------- bf16 GEMM: C[M][N] = A[M][K] * Bt[N][K]^T ----------------
template <int MODE>
__global__ __launch_bounds__(256) void gemm_bt(
    const unsigned short* __restrict__ A, const unsigned short* __restrict__ Bt,
    unsigned short* __restrict__ out0, unsigned short* __restrict__ out1,
    float* __restrict__ outf, const float* __restrict__ bias,
    int M, int N, int K) {
  __shared__ __align__(16) unsigned short A_lds[128][72];
  __shared__ __align__(16) unsigned short B_lds[128][72];
  const int tile_m = blockIdx.x * 128;
  const int tile_n = blockIdx.y * 128;
  const int tid = threadIdx.x;
  const int wid = tid >> 6, lane = tid & 63;
  const int wm = (wid >> 1) * 64, wn = (wid & 1) * 64;
  const int lr = lane & 15, lg = lane >> 4;
  f32x4 acc[4][4] = {};

  for (int k0 = 0; k0 < K; k0 += 64) {
    __syncthreads();
#pragma unroll
    for (int p = 0; p < 4; ++p) {
      int flat = p * 256 + tid;
      int row = flat >> 3, cg = (flat & 7) << 3;
      *(short8*)&A_lds[row][cg] = *(const short8*)&A[(size_t)(tile_m + row) * K + k0 + cg];
      *(short8*)&B_lds[row][cg] = *(const short8*)&Bt[(size_t)(tile_n + row) * K + k0 + cg];
    }
    __syncthreads();
    short8 a[4][2], b[4][2];
#pragma unroll
    for (int i = 0; i < 4; ++i)
#pragma unroll
      for (int t = 0; t < 2; ++t) {
        a[i][t] = *(const short8*)&A_lds[wm + i * 16 + lr][t * 32 + lg * 8];
        b[i][t] = *(const short8*)&B_lds[wn + i * 16 + lr][t * 32 + lg * 8];
      }
#pragma unroll
    for (int i = 0; i < 4; ++i)
#pragma unroll
      for (int j = 0; j < 4; ++j)
#pragma unroll
        for (int t = 0; t < 2; ++t)
          acc[i][j] = __builtin_amdgcn_mfma_f32_16x16x32_bf16(a[i][t], b[j][t], acc[i][j], 0, 0, 0);
  }

#pragma unroll
  for (int i = 0; i < 4; ++i)
#pragma unroll
    for (int j = 0; j < 4; ++j)
#pragma unroll
      for (int r = 0; r < 4; ++r) {
        int m = tile_m + wm + i * 16 + lg * 4 + r;
        int n = tile_n + wn + j * 16 + lr;
        float v = acc[i][j][r];
        if (MODE == 0) {
          int b = m >> 11, q = m & 2047;
          int h = n >> 6, d = n & 63;
          out0[((size_t)((b * 12 + h) * 2048 + q) << 6) + d] = f2bf(v);
        } else if (MODE == 1) {
          int b = m >> 11, kv = m & 2047;
          if (n < 768) {
            int h = n >> 6, d = n & 63;
            out0[((size_t)((b * 12 + h) * 2048 + kv) << 6) + d] = f2bf(v);
          } else {
            int h = (n - 768) >> 6, d = n & 63;
            out1[((size_t)((b * 12 + h) * 64 + d) << 11) + kv] = f2bf(v);
          }
        } else {
          outf[(size_t)m * N + n] = v + bias[n];
        }
      }
}

// ---------------- flash attention: in-block KV-split x4, reg-resident K/V ----------------
// Q: [B,H,Nq,D] bf16; Kb: [B,H,Nkv,D] bf16; Vt: [B,H,D,Nkv] bf16
// X out: [B,Nq,H*D] bf16.  softmax(QK^T * s) V * s, s = 0.125
// 256 thr = 4 independent waves; wave s handles KV slice [512s, 512s+512) of the
// SAME (bh, q-block) with the no-barrier reg-resident loop. One barrier at the
// end; partials (m, l, O) merged through LDS; wave w writes d-range [16w,16w+16).
// launch_bounds min-waves/EU = 2 (VGPR cap 256): R5's =4 capped at 128 and
// spilled ~180 live VGPRs to scratch (518 MB WRITE_SIZE, 2.2x regression).
__global__ __launch_bounds__(256, 2) void attn_fwd(
    const unsigned short* __restrict__ Q, const unsigned short* __restrict__ Kb,
    const unsigned short* __restrict__ Vt, unsigned short* __restrict__ X) {
  __shared__ __align__(16) float O_lds[4][32][64];
  __shared__ float m_lds[4][32];
  __shared__ float l_lds[4][64];
  const int bid = blockIdx.x;
  const int bh = bid % 24;           // bid%8 == bh%8 -> 3 heads per XCD L2
  const int q0 = (bid / 24) * 32;
  const int tid = threadIdx.x;
  const int wid = tid >> 6;          // KV slice index
  const int lane = tid & 63;
  const int l31 = lane & 31, hi = lane >> 5;
  const int kvS = wid * 512;
  const float Cc = 0.18033688011112042f;   // 0.125 * log2(e)
  const float THRS = 44.3614195558365f;    // 8 / Cc (defer-max threshold)

  const unsigned short* Kbase = Kb + (size_t)bh * (2048 * 64);
  const unsigned short* Vbase = Vt + (size_t)bh * (64 * 2048);

  // Q frags: B-operand; lane holds Q[q=l31][d = t*16 + hi*8 + e]
  short8 qf[4];
  {
    const unsigned short* Qp = Q + ((size_t)bh * 2048 + q0 + l31) * 64 + hi * 8;
#pragma unroll
    for (int t = 0; t < 4; ++t) qf[t] = *(const short8*)&Qp[t * 16];
  }

  f32x16 accO0 = {}, accO1 = {};      // O^T[d = dt*32 + crow(r,hi)][q = l31]
  float m_run = -1e30f, l_run = 0.f;  // l_run: per-half partial sum

  short8 kA[8], kB[8], vf[8];
  // prologue: K rows kvS..+63 -> kA
#pragma unroll
  for (int t = 0; t < 4; ++t) {
    kA[t]     = *(const short8*)&Kbase[(size_t)(kvS + l31) * 64 + t * 16 + hi * 8];
    kA[4 + t] = *(const short8*)&Kbase[(size_t)(kvS + 32 + l31) * 64 + t * 16 + hi * 8];
  }

#define ATTN_BODY(KC, KN, IT)                                                          \
  {                                                                                    \
    const int kv0 = kvS + (IT) * 64;                                                   \
    const int kvn = kvS + (((IT) < 7) ? ((IT) + 1) * 64 : 0);                          \
    _Pragma("unroll")                                                                  \
    for (int t = 0; t < 4; ++t) {                                                      \
      KN[t]     = *(const short8*)&Kbase[(size_t)(kvn + l31) * 64 + t * 16 + hi * 8];  \
      KN[4 + t] = *(const short8*)&Kbase[(size_t)(kvn + 32 + l31) * 64 + t * 16 + hi * 8]; \
    }                                                                                  \
    _Pragma("unroll")                                                                  \
    for (int s = 0; s < 4; ++s) {                                                      \
      vf[s]     = *(const short8*)&Vbase[(size_t)l31 * 2048 + kv0 + s * 16 + hi * 8];  \
      vf[4 + s] = *(const short8*)&Vbase[(size_t)(32 + l31) * 2048 + kv0 + s * 16 + hi * 8]; \
    }                                                                                  \
    f32x16 S0 = {}, S1 = {};                                                           \
    _Pragma("unroll")                                                                  \
    for (int t = 0; t < 4; ++t) {                                                      \
      S0 = __builtin_amdgcn_mfma_f32_32x32x16_bf16(KC[t], qf[t], S0, 0, 0, 0);         \
      S1 = __builtin_amdgcn_mfma_f32_32x32x16_bf16(KC[4 + t], qf[t], S1, 0, 0, 0);     \
    }                                                                                  \
    float rmax = fmaxf(S0[0], S1[0]);                                                  \
    _Pragma("unroll")                                                                  \
    for (int r = 1; r < 16; ++r) rmax = fmaxf(rmax, fmaxf(S0[r], S1[r]));              \
    rmax = fmaxf(rmax, __shfl_xor(rmax, 32));                                          \
    if (!__all(rmax <= m_run + THRS)) {                                                \
      float mnew = fmaxf(m_run, rmax);                                                 \
      float alpha = exp2f((m_run - mnew) * Cc);                                        \
      m_run = mnew;                                                                    \
      l_run *= alpha;                                                                  \
      _Pragma("unroll")                                                                \
      for (int r = 0; r < 16; ++r) { accO0[r] *= alpha; accO1[r] *= alpha; }           \
    }                                                                                  \
    float sum = 0.f;                                                                   \
    _Pragma("unroll")                                                                  \
    for (int r = 0; r < 16; ++r) {                                                     \
      S0[r] = exp2f((S0[r] - m_run) * Cc);                                             \
      S1[r] = exp2f((S1[r] - m_run) * Cc);                                             \
      sum += S0[r] + S1[r];                                                            \
    }                                                                                  \
    l_run += sum;                                                                      \
    unsigned w0[8], w1[8];                                                             \
    _Pragma("unroll")                                                                  \
    for (int j = 0; j < 4; ++j) {                                                      \
      w0[j]     = cvt_pk_bf16(S0[4 * j],     S0[4 * j + 1]);                           \
      w1[j]     = cvt_pk_bf16(S0[4 * j + 2], S0[4 * j + 3]);                           \
      w0[4 + j] = cvt_pk_bf16(S1[4 * j],     S1[4 * j + 1]);                           \
      w1[4 + j] = cvt_pk_bf16(S1[4 * j + 2], S1[4 * j + 3]);                           \
    }                                                                                  \
    _Pragma("unroll")                                                                  \
    for (int s = 0; s < 4; ++s) {                                                      \
      unsigned A0 = w0[2 * s], B0 = w0[2 * s + 1];                                     \
      unsigned A1 = w1[2 * s], B1 = w1[2 * s + 1];                                     \
      unsigned A0s = (unsigned)__shfl_xor((int)A0, 32);                                \
      unsigned B0s = (unsigned)__shfl_xor((int)B0, 32);                                \
      unsigned A1s = (unsigned)__shfl_xor((int)A1, 32);                                \
      unsigned B1s = (unsigned)__shfl_xor((int)B1, 32);                                \
      unsigned X0 = hi ? B0s : A0;                                                     \
      unsigned X1 = hi ? B1s : A1;                                                     \
      unsigned X2 = hi ? B0 : A0s;                                                     \
      unsigned X3 = hi ? B1 : A1s;                                                     \
      u32x4 pw = {X0, X1, X2, X3};                                                     \
      short8 pfrag = __builtin_bit_cast(short8, pw);                                   \
      accO0 = __builtin_amdgcn_mfma_f32_32x32x16_bf16(vf[s], pfrag, accO0, 0, 0, 0);   \
      accO1 = __builtin_amdgcn_mfma_f32_32x32x16_bf16(vf[4 + s], pfrag, accO1, 0, 0, 0); \
    }                                                                                  \
  }

  for (int i = 0; i < 4; ++i) {
    ATTN_BODY(kA, kB, 2 * i);
    ATTN_BODY(kB, kA, 2 * i + 1);
  }
#undef ATTN_BODY

  // ---- write partials to LDS ----
#pragma unroll
  for (int dt = 0; dt < 2; ++dt) {
    const f32x16& acc = dt ? accO1 : accO0;
#pragma unroll
    for (int r = 0; r < 16; ++r)
      O_lds[wid][dt * 16 + r][hi * 32 + l31] = acc[r];
  }
  if (hi == 0) m_lds[wid][l31] = m_run;
  l_lds[wid][hi * 32 + l31] = l_run;
  __syncthreads();

  // ---- combine across slices; wave w covers d in [16w,16w+16), lane: j=hi*8.. ----
  float M = m_lds[0][l31];
#pragma unroll
  for (int s = 1; s < 4; ++s) M = fmaxf(M, m_lds[s][l31]);
  float wsc[4];
  float ltot = 0.f;
#pragma unroll
  for (int s = 0; s < 4; ++s) {
    wsc[s] = exp2f((m_lds[s][l31] - M) * Cc);
    ltot += wsc[s] * (l_lds[s][l31] + l_lds[s][32 + l31]);
  }
  const float inv = 0.125f / ltot;  // faithful quirk: extra scale
  const int b = bh / 12, h = bh % 12;
  short8 os;
#pragma unroll
  for (int j = 0; j < 8; ++j) {
    const int d = wid * 16 + hi * 8 + j;
    const int dt = d >> 5, crow = d & 31;
    const int hs = (crow >> 2) & 1;
    const int r = (crow & 3) | ((crow >> 3) << 2);
    float acc = 0.f;
#pragma unroll
    for (int s = 0; s < 4; ++s) acc += wsc[s] * O_lds[s][dt * 16 + r][hs * 32 + l31];
    os[j] = (short)f2bf(acc * inv);
  }
  unsigned short* Xp = X + ((size_t)b * 2048 + q0 + l31) * 768 + h * 64 + wid * 16 + hi * 8;
  *(short8*)Xp = os;
}

extern "C" void kernel_launch(void* const* d_in, const int* in_sizes, int n_in,
                              void* d_out, int out_size, void* d_ws, size_t ws_size,
                              hipStream_t stream) {
  const float* q_token  = (const float*)d_in[0];
  const float* kv_token = (const float*)d_in[1];
  const float* Wq    = (const float*)d_in[2];
  const float* Wkv   = (const float*)d_in[3];
  const float* Wproj = (const float*)d_in[4];
  const float* bproj = (const float*)d_in[5];
  float* out = (float*)d_out;

  unsigned short* qb   = (unsigned short*)d_ws;   // [4096][768]
  unsigned short* kvb  = qb   + 3145728;          // [4096][768]
  unsigned short* wqT  = kvb  + 3145728;          // [768][768]
  unsigned short* wkvT = wqT  + 589824;           // [1536][768]
  unsigned short* wpT  = wkvT + 1179648;          // [768][768]
  unsigned short* Qb   = wpT  + 589824;           // [B,H,Nq,D]
  unsigned short* Kbf  = Qb   + 3145728;          // [B,H,Nkv,D]
  unsigned short* Vtb  = Kbf  + 3145728;          // [B,H,D,Nkv]
  unsigned short* Xb   = Vtb  + 3145728;          // [B,Nq,C]

  cvt_copy<<<3072, 256, 0, stream>>>(q_token, qb, 786432);
  cvt_copy<<<3072, 256, 0, stream>>>(kv_token, kvb, 786432);
  transpose_cvt<<<dim3(24, 24), dim3(32, 8), 0, stream>>>(Wq, wqT, 768, 768);
  transpose_cvt<<<dim3(48, 24), dim3(32, 8), 0, stream>>>(Wkv, wkvT, 768, 1536);
  transpose_cvt<<<dim3(24, 24), dim3(32, 8), 0, stream>>>(Wproj, wpT, 768, 768);

  gemm_bt<0><<<dim3(32, 6),  256, 0, stream>>>(qb,  wqT,  Qb,  nullptr, nullptr, nullptr, 4096, 768, 768);
  gemm_bt<1><<<dim3(32, 12), 256, 0, stream>>>(kvb, wkvT, Kbf, Vtb,     nullptr, nullptr, 4096, 1536, 768);

  attn_fwd<<<1536, 256, 0, stream>>>(Qb, Kbf, Vtb, Xb);

  gemm_bt<2><<<dim3(32, 6), 256, 0, stream>>>(Xb, wpT, nullptr, nullptr, out, bproj, 4096, 768, 768);
}